// Round 13
// baseline (103.761 us; speedup 1.0000x reference)
//
#include <hip/hip_runtime.h>
#include <hip/hip_bf16.h>

#define C_DIM 512
#define S_DIM 1024
#define NH 8
#define HD 64  // head dim

typedef __attribute__((ext_vector_type(8))) short bf16x8;            // MFMA A/B frag (8 bf16)
typedef __attribute__((ext_vector_type(8))) unsigned short u16x8;
typedef __attribute__((ext_vector_type(4))) unsigned short u16x4;
typedef __attribute__((ext_vector_type(4))) float f32x4;

__device__ __forceinline__ unsigned short f2b_hw(float f) {  // fp32 -> bf16 RNE (HW cvt)
  __hip_bfloat16 h = __float2bfloat16(f);
  return __builtin_bit_cast(unsigned short, h);
}

__device__ __forceinline__ f32x4 mfma16(bf16x8 a, bf16x8 b, f32x4 c) {
  return __builtin_amdgcn_mfma_f32_16x16x32_bf16(a, b, c, 0, 0, 0);
}

__device__ __forceinline__ void gload_lds16(const unsigned short* g, unsigned short* l) {
  __builtin_amdgcn_global_load_lds(
      (const __attribute__((address_space(1))) unsigned int*)g,
      (__attribute__((address_space(3))) unsigned int*)l, 16, 0, 0);
}

// ---------------------------------------------------------------------------
// prep: blocks [0,1024): convert Wqkv (Q-rows pre-scaled by (1/8)*log2e) and
//       Wo fp32->bf16.  blocks [1024,2048): transpose x [b][c][s] fp32 ->
//       xT [b][s][c] bf16 via 64x64 LDS tile.
// ---------------------------------------------------------------------------
__global__ __launch_bounds__(256) void prep(
    const float* __restrict__ x, const float* __restrict__ Wqkv,
    const float* __restrict__ Wo,
    unsigned short* __restrict__ WqkvB, unsigned short* __restrict__ WoB,
    unsigned short* __restrict__ xT)
{
  __shared__ float T[64][65];
  const int bid = blockIdx.x;
  if (bid < 1024) {
    const int i = bid * 256 + threadIdx.x;  // handles 4 elements
    const float* src;
    unsigned short* dst;
    int off;
    float mul = 1.0f;
    if (i < 196608) {
      src = Wqkv; dst = WqkvB; off = i * 4;
      const int o = off >> 9;               // row of Wqkv
      if ((o % 192) < 64) mul = 0.18033688011112042f;  // Q rows: (1/8)*log2(e)
    } else {
      src = Wo; dst = WoB; off = (i - 196608) * 4;
    }
    const float4 v = *(const float4*)(src + off);
    const u16x4 pk = {f2b_hw(v.x * mul), f2b_hw(v.y * mul),
                      f2b_hw(v.z * mul), f2b_hw(v.w * mul)};
    *(u16x4*)(dst + off) = pk;
  } else {
    const int idx = bid - 1024;
    const int st = idx & 15, ct = (idx >> 4) & 7, b = idx >> 7;
    const int c0 = ct * 64, s0 = st * 64;
    const int tr = threadIdx.x >> 4, tc4 = (threadIdx.x & 15) * 4;
#pragma unroll
    for (int rep = 0; rep < 4; ++rep) {
      const int c = rep * 16 + tr;
      *(float4*)&T[c][tc4] =
          *(const float4*)(x + ((size_t)(b * C_DIM + c0 + c)) * S_DIM + s0 + tc4);
    }
    __syncthreads();
#pragma unroll
    for (int rep = 0; rep < 4; ++rep) {
      const int s = rep * 16 + tr;
      const u16x4 pk = {f2b_hw(T[tc4 + 0][s]), f2b_hw(T[tc4 + 1][s]),
                        f2b_hw(T[tc4 + 2][s]), f2b_hw(T[tc4 + 3][s])};
      *(u16x4*)(xT + ((size_t)(b * S_DIM + s0 + s)) * C_DIM + c0 + tc4) = pk;
    }
  }
}

// ---------------------------------------------------------------------------
// bf16 MFMA GEMM: C[o][s] = sum_c A[o][c] * Bm[b][s][c]   (both k-contiguous)
// 128x128 tile, BK=64, 4 waves (2x2 of 64x64), 16x16x32 MFMA. (m97 structure)
// MODE 0: M=1536, scatter bf16 Q/K -> [bh][s][d]; Vt -> [bh][d][s] with the
//         within-64 column permutation p = (s&35)|((s&12)<<1)|((s&16)>>2)
//         so attn's PV A-fragment is one contiguous ds_read_b128.
// MODE 1: M=512,  y = C + bo + resid (fp32, [b][o][s])
// ---------------------------------------------------------------------------
template <int MODE>
__global__ __launch_bounds__(256) void mfma_proj(
    const unsigned short* __restrict__ A, const unsigned short* __restrict__ Bm,
    unsigned short* __restrict__ Q, unsigned short* __restrict__ K,
    unsigned short* __restrict__ Vt,
    float* __restrict__ y, const float* __restrict__ bo,
    const float* __restrict__ resid)
{
  const int b = blockIdx.z, ot = blockIdx.y, st = blockIdx.x;
  const int o0 = ot * 128, s0 = st * 128;
  const int tid = threadIdx.x;
  const int w = tid >> 6, lane = tid & 63;
  const int g = lane >> 4, j16 = lane & 15;
  const int wr = w >> 1, wc = w & 1;

  __shared__ __align__(16) unsigned short lds[2048 * 8];  // 32KB: A[128][64] | B[128][64]
  char* const Al = (char*)lds;
  char* const Bl = (char*)lds + 16384;

  f32x4 acc[4][4];
#pragma unroll
  for (int mt = 0; mt < 4; ++mt)
#pragma unroll
    for (int nt = 0; nt < 4; ++nt) {
      acc[mt][nt].x = 0.f; acc[mt][nt].y = 0.f;
      acc[mt][nt].z = 0.f; acc[mt][nt].w = 0.f;
    }

  for (int k0 = 0; k0 < C_DIM; k0 += 64) {
    __syncthreads();  // prev compute done reading LDS
#pragma unroll
    for (int it = 0; it < 8; ++it) {
      const int chunk = it * 256 + tid;     // 0..2047, 16B each
      const int cid = chunk & 1023;
      const int row = cid >> 3;
      const int colb = (cid & 7) << 4;
      const int srcb = colb ^ ((row & 7) << 4);  // inverse swizzle on source
      const unsigned short* gp;
      if (it < 4) gp = A + (size_t)(o0 + row) * C_DIM + k0 + (srcb >> 1);
      else        gp = Bm + ((size_t)(b * S_DIM) + s0 + row) * C_DIM + k0 + (srcb >> 1);
      gload_lds16(gp, lds + (size_t)(it * 256 + w * 64) * 8);
    }
    __syncthreads();  // drains vmcnt -> LDS ready

#pragma unroll
    for (int ks = 0; ks < 2; ++ks) {
      bf16x8 af[4], bfr[4];
#pragma unroll
      for (int mt = 0; mt < 4; ++mt) {
        const int r = wr * 64 + mt * 16 + j16;
        af[mt] = __builtin_bit_cast(
            bf16x8, *(const u16x8*)(Al + r * 128 + ((ks * 64 + g * 16) ^ ((r & 7) << 4))));
      }
#pragma unroll
      for (int nt = 0; nt < 4; ++nt) {
        const int r = wc * 64 + nt * 16 + j16;
        bfr[nt] = __builtin_bit_cast(
            bf16x8, *(const u16x8*)(Bl + r * 128 + ((ks * 64 + g * 16) ^ ((r & 7) << 4))));
      }
#pragma unroll
      for (int mt = 0; mt < 4; ++mt)
#pragma unroll
        for (int nt = 0; nt < 4; ++nt)
          acc[mt][nt] = mfma16(af[mt], bfr[nt], acc[mt][nt]);
    }
  }

  // epilogue: element o = o0 + wr*64 + mt*16 + g*4 + q ; s = s0 + wc*64 + nt*16 + j16
#pragma unroll
  for (int mt = 0; mt < 4; ++mt) {
    const int ob = o0 + wr * 64 + mt * 16 + g * 4;
    if (MODE == 0) {
      // 16-aligned o-blocks never cross the 64/192 boundaries -> uniform per mt
      const int head = ob / 192, type = (ob % 192) >> 6, d = ob & 63;
      const int bh = b * NH + head;
      if (type < 2) {  // Q (pre-scaled via W) or K -> [bh][s][d]
        unsigned short* const dst = (type == 0) ? Q : K;
#pragma unroll
        for (int nt = 0; nt < 4; ++nt) {
          const int s = s0 + wc * 64 + nt * 16 + j16;
          const f32x4 a = acc[mt][nt];
          const u16x4 pk = {f2b_hw(a.x), f2b_hw(a.y), f2b_hw(a.z), f2b_hw(a.w)};
          *(u16x4*)(dst + ((size_t)bh * S_DIM + s) * HD + d) = pk;
        }
      } else {  // V -> [bh][d][s] with permuted within-64 column order
#pragma unroll
        for (int nt = 0; nt < 4; ++nt) {
          const int spos = nt * 16 + j16;  // position within the 64-block
          const int p = (spos & 35) | ((spos & 12) << 1) | ((spos & 16) >> 2);
          const size_t col = (size_t)(s0 + wc * 64 + p);
          const f32x4 a = acc[mt][nt];
#pragma unroll
          for (int q = 0; q < 4; ++q)
            Vt[((size_t)bh * HD + d + q) * S_DIM + col] = f2b_hw(a[q]);
        }
      }
    } else {
#pragma unroll
      for (int nt = 0; nt < 4; ++nt) {
        const int s = s0 + wc * 64 + nt * 16 + j16;
#pragma unroll
        for (int q = 0; q < 4; ++q) {
          const int o = ob + q;
          const size_t idx = ((size_t)(b * C_DIM + o)) * S_DIM + s;
          y[idx] = acc[mt][nt][q] + bo[o] + resid[idx];
        }
      }
    }
  }
}

// ---------------------------------------------------------------------------
// MFMA flash attention — KVBLK=128: 8 staged tiles (was 16), 2 buffers of
// (K[128][64] 16KB + V[64][256B] 16KB) = 64KB LDS, ONE __syncthreads per
// 128 keys (the prefetch issued last iter had a full ~2000-cyc compute phase
// to land, so the implicit vmcnt(0) drain is free). Each tile computed as two
// 64-key sub-phases reusing sacc/pf4 (VGPR stays ~96 — R9 lesson).
// K swizzle (row&7)<<4 (128B rows); V swizzle (row&15)<<4 (256B rows, 2-way
// bank aliasing = free per m136); both applied as inverse on the global src.
// P fully in registers (PV k-slot map key = ks*32+(idx>>2)*16+g*4+(idx&3),
// ks = sub*2+ks2; Vt global col-perm per 64-block unchanged).
// Normalization (1/l) in the epilogue (l is per (head,q) — R5 lesson).
// Grid (bh, qb): 64 x 8 = 512 blocks, 256 thr (4 waves, nt=2: 32 q/wave).
// ---------------------------------------------------------------------------
__global__ __launch_bounds__(256) void attn_mfma(
    const unsigned short* __restrict__ Qg, const unsigned short* __restrict__ Kg,
    const unsigned short* __restrict__ Vg, unsigned short* __restrict__ AOt)
{
  const int bh = blockIdx.x;   // 0..63 (fast dim -> same-XCD KV sharing)
  const int qb = blockIdx.y;   // 0..7
  const int b = bh >> 3, head = bh & 7;
  const int tid = threadIdx.x;
  const int w = tid >> 6, lane = tid & 63;
  const int g = lane >> 4, j16 = lane & 15;
  const int qw0 = qb * 128 + w * 32;  // this wave's 32 q-rows

  // [buf][ K 16KB | V 16KB ]; buf stride 32KB
  __shared__ __align__(16) unsigned short KV[2][2][8192];

  // Q B-fragments resident in registers: j=q=lane&15, k-slot (g,reg)->d
  bf16x8 qf[2][2];
#pragma unroll
  for (int nt = 0; nt < 2; ++nt)
#pragma unroll
    for (int ks = 0; ks < 2; ++ks)
      qf[nt][ks] = __builtin_bit_cast(
          bf16x8, *(const u16x8*)(Qg + ((size_t)bh * S_DIM + qw0 + nt * 16 + j16) * HD +
                                  ks * 32 + g * 8));

  // staging per 128-key tile: K 1024 chunks + V 1024 chunks over 256 thr
  // = 4+4 gload_lds/thread. dst = linear chunk*16 (wave-uniform base + lane*16).
  auto STAGE = [&](int buf, int k0) {
    unsigned short* const Kd = &KV[buf][0][0];
    unsigned short* const Vd = &KV[buf][1][0];
#pragma unroll
    for (int it = 0; it < 4; ++it) {
      const int cid = it * 256 + tid;
      // K chunk: row 0..127 (key), 128B rows, swizzle (row&7)<<4
      const int krow = cid >> 3;
      const int ksrc = ((cid & 7) << 4) ^ ((krow & 7) << 4);
      gload_lds16(Kg + ((size_t)bh * S_DIM + k0 + krow) * HD + (ksrc >> 1),
                  Kd + (size_t)(it * 256 + w * 64) * 8);
      // V chunk: row 0..63 (d), 256B rows, swizzle (row&15)<<4
      const int vrow = cid >> 4;
      const int vsrc = ((cid & 15) << 4) ^ ((vrow & 15) << 4);
      gload_lds16(Vg + ((size_t)bh * HD + vrow) * S_DIM + k0 + (vsrc >> 1),
                  Vd + (size_t)(it * 256 + w * 64) * 8);
    }
  };

  f32x4 oacc[4][2];
#pragma unroll
  for (int mt = 0; mt < 4; ++mt)
#pragma unroll
    for (int nt = 0; nt < 2; ++nt) {
      oacc[mt][nt].x = 0.f; oacc[mt][nt].y = 0.f;
      oacc[mt][nt].z = 0.f; oacc[mt][nt].w = 0.f;
    }
  float lsum[2] = {0.f, 0.f};

  STAGE(0, 0);

#pragma unroll
  for (int kt = 0; kt < 8; ++kt) {
    __syncthreads();  // drains prefetch (issued a full tile-compute ago) +
                      // gates overwrite of the buffer read last iteration
    if (kt < 7) STAGE((kt + 1) & 1, (kt + 1) * 128);

    const char* const Kl = (const char*)&KV[kt & 1][0][0];
    const char* const Vl = (const char*)&KV[kt & 1][1][0];

#pragma unroll
    for (int sub = 0; sub < 2; ++sub) {
      // ---- S^T = K · Q^T  (key = sub*64 + mt*16+g*4+reg, q = nt*16+j16)
      f32x4 sacc[4][2];
      __builtin_amdgcn_s_setprio(1);
#pragma unroll
      for (int mt = 0; mt < 4; ++mt) {
        const int row = sub * 64 + mt * 16 + j16;
        const int sw = (row & 7) << 4;
        const bf16x8 kf0 = __builtin_bit_cast(
            bf16x8, *(const u16x8*)(Kl + row * 128 + ((g * 16) ^ sw)));
#pragma unroll
        for (int nt = 0; nt < 2; ++nt) {
          f32x4 z; z.x = 0.f; z.y = 0.f; z.z = 0.f; z.w = 0.f;
          sacc[mt][nt] = mfma16(kf0, qf[nt][0], z);
        }
        const bf16x8 kf1 = __builtin_bit_cast(
            bf16x8, *(const u16x8*)(Kl + row * 128 + ((64 + g * 16) ^ sw)));
#pragma unroll
        for (int nt = 0; nt < 2; ++nt)
          sacc[mt][nt] = mfma16(kf1, qf[nt][1], sacc[mt][nt]);
      }
      __builtin_amdgcn_s_setprio(0);

      // ---- exp2 + pack P in registers: pf4[nt][mt] = bf16 of p[reg 0..3]
      u16x4 pf4[2][4];
#pragma unroll
      for (int mt = 0; mt < 4; ++mt)
#pragma unroll
        for (int nt = 0; nt < 2; ++nt) {
          f32x4 p;
          p.x = exp2f(sacc[mt][nt].x);
          p.y = exp2f(sacc[mt][nt].y);
          p.z = exp2f(sacc[mt][nt].z);
          p.w = exp2f(sacc[mt][nt].w);
          lsum[nt] += (p.x + p.y) + (p.z + p.w);
          pf4[nt][mt] = u16x4{f2b_hw(p.x), f2b_hw(p.y), f2b_hw(p.z), f2b_hw(p.w)};
        }

      // ---- O^T += V^T · P^T  (keys sub*64..sub*64+63; V cols sub*128 bytes on)
      __builtin_amdgcn_s_setprio(1);
#pragma unroll
      for (int ks2 = 0; ks2 < 2; ++ks2) {
        bf16x8 pfr[2];
#pragma unroll
        for (int nt = 0; nt < 2; ++nt)
          pfr[nt] = __builtin_bit_cast(
              bf16x8, __builtin_shufflevector(pf4[nt][2 * ks2], pf4[nt][2 * ks2 + 1],
                                              0, 1, 2, 3, 4, 5, 6, 7));
#pragma unroll
        for (int mt = 0; mt < 4; ++mt) {
          const int vrow = mt * 16 + j16;           // d row, 256B pitch
          const int col = (sub * 128 + ks2 * 64 + g * 16) ^ ((vrow & 15) << 4);
          const bf16x8 vf = __builtin_bit_cast(
              bf16x8, *(const u16x8*)(Vl + vrow * 256 + col));
#pragma unroll
          for (int nt = 0; nt < 2; ++nt)
            oacc[mt][nt] = mfma16(vf, pfr[nt], oacc[mt][nt]);
        }
      }
      __builtin_amdgcn_s_setprio(0);
    }
  }

  // softmax denominator: q col = lane&15; reduce across the 4 lane-groups
#pragma unroll
  for (int nt = 0; nt < 2; ++nt) {
    lsum[nt] += __shfl_xor(lsum[nt], 16);
    lsum[nt] += __shfl_xor(lsum[nt], 32);
    lsum[nt] = 1.f / lsum[nt];
  }

  // write NORMALIZED AO^T [b][s][c] bf16, c = head*64 + d; d = mt*16+g*4+r
#pragma unroll
  for (int mt = 0; mt < 4; ++mt)
#pragma unroll
    for (int nt = 0; nt < 2; ++nt) {
      const int q = qw0 + nt * 16 + j16;
      const f32x4 a = oacc[mt][nt];
      const float rl = lsum[nt];
      const u16x4 pk = {f2b_hw(a.x * rl), f2b_hw(a.y * rl), f2b_hw(a.z * rl), f2b_hw(a.w * rl)};
      *(u16x4*)(AOt + ((size_t)(b * S_DIM + q)) * C_DIM + head * HD + mt * 16 + g * 4) = pk;
    }
}

extern "C" void kernel_launch(void* const* d_in, const int* in_sizes, int n_in,
                              void* d_out, int out_size, void* d_ws, size_t ws_size,
                              hipStream_t stream) {
  const float* x    = (const float*)d_in[0];
  const float* Wqkv = (const float*)d_in[1];
  const float* Wo   = (const float*)d_in[2];
  const float* bo   = (const float*)d_in[3];
  float* y = (float*)d_out;

  unsigned short* WqkvB = (unsigned short*)d_ws;           // 786432
  unsigned short* WoB   = WqkvB + 786432;                  // 262144
  unsigned short* xT    = WoB + 262144;                    // 4194304
  unsigned short* Q     = xT + 4194304;                    // 4194304
  unsigned short* K     = Q + 4194304;
  unsigned short* Vt    = K + 4194304;
  unsigned short* AOt   = Vt + 4194304;                    // 4194304

  prep<<<dim3(2048), 256, 0, stream>>>(x, Wqkv, Wo, WqkvB, WoB, xT);
  mfma_proj<0><<<dim3(8, 12, 8), 256, 0, stream>>>(WqkvB, xT, Q, K, Vt,
                                                   nullptr, nullptr, nullptr);
  attn_mfma<<<dim3(64, 8), 256, 0, stream>>>(Q, K, Vt, AOt);
  mfma_proj<1><<<dim3(8, 4, 8), 256, 0, stream>>>(WoB, AOt, nullptr, nullptr, nullptr,
                                                  y, bo, x);
}

// Round 14
// 86.551 us; speedup vs baseline: 1.1988x; 1.1988x over previous
//
#include <hip/hip_runtime.h>
#include <hip/hip_bf16.h>

#define C_DIM 512
#define S_DIM 1024
#define NH 8
#define HD 64  // head dim

typedef __attribute__((ext_vector_type(8))) short bf16x8;            // MFMA A/B frag (8 bf16)
typedef __attribute__((ext_vector_type(8))) unsigned short u16x8;
typedef __attribute__((ext_vector_type(4))) unsigned short u16x4;
typedef __attribute__((ext_vector_type(4))) float f32x4;

__device__ __forceinline__ unsigned short f2b_hw(float f) {  // fp32 -> bf16 RNE (HW cvt)
  __hip_bfloat16 h = __float2bfloat16(f);
  return __builtin_bit_cast(unsigned short, h);
}

__device__ __forceinline__ f32x4 mfma16(bf16x8 a, bf16x8 b, f32x4 c) {
  return __builtin_amdgcn_mfma_f32_16x16x32_bf16(a, b, c, 0, 0, 0);
}

__device__ __forceinline__ void gload_lds16(const unsigned short* g, unsigned short* l) {
  __builtin_amdgcn_global_load_lds(
      (const __attribute__((address_space(1))) unsigned int*)g,
      (__attribute__((address_space(3))) unsigned int*)l, 16, 0, 0);
}

// ---------------------------------------------------------------------------
// prep: blocks [0,1024): convert Wqkv (Q-rows pre-scaled by (1/8)*log2e) and
//       Wo fp32->bf16.  blocks [1024,2048): transpose x [b][c][s] fp32 ->
//       xT [b][s][c] bf16 via 64x64 LDS tile.
// ---------------------------------------------------------------------------
__global__ __launch_bounds__(256) void prep(
    const float* __restrict__ x, const float* __restrict__ Wqkv,
    const float* __restrict__ Wo,
    unsigned short* __restrict__ WqkvB, unsigned short* __restrict__ WoB,
    unsigned short* __restrict__ xT)
{
  __shared__ float T[64][65];
  const int bid = blockIdx.x;
  if (bid < 1024) {
    const int i = bid * 256 + threadIdx.x;  // handles 4 elements
    const float* src;
    unsigned short* dst;
    int off;
    float mul = 1.0f;
    if (i < 196608) {
      src = Wqkv; dst = WqkvB; off = i * 4;
      const int o = off >> 9;               // row of Wqkv
      if ((o % 192) < 64) mul = 0.18033688011112042f;  // Q rows: (1/8)*log2(e)
    } else {
      src = Wo; dst = WoB; off = (i - 196608) * 4;
    }
    const float4 v = *(const float4*)(src + off);
    const u16x4 pk = {f2b_hw(v.x * mul), f2b_hw(v.y * mul),
                      f2b_hw(v.z * mul), f2b_hw(v.w * mul)};
    *(u16x4*)(dst + off) = pk;
  } else {
    const int idx = bid - 1024;
    const int st = idx & 15, ct = (idx >> 4) & 7, b = idx >> 7;
    const int c0 = ct * 64, s0 = st * 64;
    const int tr = threadIdx.x >> 4, tc4 = (threadIdx.x & 15) * 4;
#pragma unroll
    for (int rep = 0; rep < 4; ++rep) {
      const int c = rep * 16 + tr;
      *(float4*)&T[c][tc4] =
          *(const float4*)(x + ((size_t)(b * C_DIM + c0 + c)) * S_DIM + s0 + tc4);
    }
    __syncthreads();
#pragma unroll
    for (int rep = 0; rep < 4; ++rep) {
      const int s = rep * 16 + tr;
      const u16x4 pk = {f2b_hw(T[tc4 + 0][s]), f2b_hw(T[tc4 + 1][s]),
                        f2b_hw(T[tc4 + 2][s]), f2b_hw(T[tc4 + 3][s])};
      *(u16x4*)(xT + ((size_t)(b * S_DIM + s0 + s)) * C_DIM + c0 + tc4) = pk;
    }
  }
}

// ---------------------------------------------------------------------------
// bf16 MFMA GEMM: C[o][s] = sum_c A[o][c] * Bm[b][s][c]   (both k-contiguous)
// 128x128 tile, BK=64, 4 waves (2x2 of 64x64), 16x16x32 MFMA. (m97 structure)
// MODE 0: M=1536, scatter bf16 Q/K -> [bh][s][d]; Vt -> [bh][d][s] with the
//         within-64 column permutation p = (s&35)|((s&12)<<1)|((s&16)>>2)
//         so attn's PV A-fragment is one contiguous ds_read_b128.
// MODE 1: M=512,  y = C + bo + resid (fp32, [b][o][s])
// ---------------------------------------------------------------------------
template <int MODE>
__global__ __launch_bounds__(256) void mfma_proj(
    const unsigned short* __restrict__ A, const unsigned short* __restrict__ Bm,
    unsigned short* __restrict__ Q, unsigned short* __restrict__ K,
    unsigned short* __restrict__ Vt,
    float* __restrict__ y, const float* __restrict__ bo,
    const float* __restrict__ resid)
{
  const int b = blockIdx.z, ot = blockIdx.y, st = blockIdx.x;
  const int o0 = ot * 128, s0 = st * 128;
  const int tid = threadIdx.x;
  const int w = tid >> 6, lane = tid & 63;
  const int g = lane >> 4, j16 = lane & 15;
  const int wr = w >> 1, wc = w & 1;

  __shared__ __align__(16) unsigned short lds[2048 * 8];  // 32KB: A[128][64] | B[128][64]
  char* const Al = (char*)lds;
  char* const Bl = (char*)lds + 16384;

  f32x4 acc[4][4];
#pragma unroll
  for (int mt = 0; mt < 4; ++mt)
#pragma unroll
    for (int nt = 0; nt < 4; ++nt) {
      acc[mt][nt].x = 0.f; acc[mt][nt].y = 0.f;
      acc[mt][nt].z = 0.f; acc[mt][nt].w = 0.f;
    }

  for (int k0 = 0; k0 < C_DIM; k0 += 64) {
    __syncthreads();  // prev compute done reading LDS
#pragma unroll
    for (int it = 0; it < 8; ++it) {
      const int chunk = it * 256 + tid;     // 0..2047, 16B each
      const int cid = chunk & 1023;
      const int row = cid >> 3;
      const int colb = (cid & 7) << 4;
      const int srcb = colb ^ ((row & 7) << 4);  // inverse swizzle on source
      const unsigned short* gp;
      if (it < 4) gp = A + (size_t)(o0 + row) * C_DIM + k0 + (srcb >> 1);
      else        gp = Bm + ((size_t)(b * S_DIM) + s0 + row) * C_DIM + k0 + (srcb >> 1);
      gload_lds16(gp, lds + (size_t)(it * 256 + w * 64) * 8);
    }
    __syncthreads();  // drains vmcnt -> LDS ready

#pragma unroll
    for (int ks = 0; ks < 2; ++ks) {
      bf16x8 af[4], bfr[4];
#pragma unroll
      for (int mt = 0; mt < 4; ++mt) {
        const int r = wr * 64 + mt * 16 + j16;
        af[mt] = __builtin_bit_cast(
            bf16x8, *(const u16x8*)(Al + r * 128 + ((ks * 64 + g * 16) ^ ((r & 7) << 4))));
      }
#pragma unroll
      for (int nt = 0; nt < 4; ++nt) {
        const int r = wc * 64 + nt * 16 + j16;
        bfr[nt] = __builtin_bit_cast(
            bf16x8, *(const u16x8*)(Bl + r * 128 + ((ks * 64 + g * 16) ^ ((r & 7) << 4))));
      }
#pragma unroll
      for (int mt = 0; mt < 4; ++mt)
#pragma unroll
        for (int nt = 0; nt < 4; ++nt)
          acc[mt][nt] = mfma16(af[mt], bfr[nt], acc[mt][nt]);
    }
  }

  // epilogue: element o = o0 + wr*64 + mt*16 + g*4 + q ; s = s0 + wc*64 + nt*16 + j16
#pragma unroll
  for (int mt = 0; mt < 4; ++mt) {
    const int ob = o0 + wr * 64 + mt * 16 + g * 4;
    if (MODE == 0) {
      // 16-aligned o-blocks never cross the 64/192 boundaries -> uniform per mt
      const int head = ob / 192, type = (ob % 192) >> 6, d = ob & 63;
      const int bh = b * NH + head;
      if (type < 2) {  // Q (pre-scaled via W) or K -> [bh][s][d]
        unsigned short* const dst = (type == 0) ? Q : K;
#pragma unroll
        for (int nt = 0; nt < 4; ++nt) {
          const int s = s0 + wc * 64 + nt * 16 + j16;
          const f32x4 a = acc[mt][nt];
          const u16x4 pk = {f2b_hw(a.x), f2b_hw(a.y), f2b_hw(a.z), f2b_hw(a.w)};
          *(u16x4*)(dst + ((size_t)bh * S_DIM + s) * HD + d) = pk;
        }
      } else {  // V -> [bh][d][s] with permuted within-64 column order
#pragma unroll
        for (int nt = 0; nt < 4; ++nt) {
          const int spos = nt * 16 + j16;  // position within the 64-block
          const int p = (spos & 35) | ((spos & 12) << 1) | ((spos & 16) >> 2);
          const size_t col = (size_t)(s0 + wc * 64 + p);
          const f32x4 a = acc[mt][nt];
#pragma unroll
          for (int q = 0; q < 4; ++q)
            Vt[((size_t)bh * HD + d + q) * S_DIM + col] = f2b_hw(a[q]);
        }
      }
    } else {
#pragma unroll
      for (int nt = 0; nt < 4; ++nt) {
        const int s = s0 + wc * 64 + nt * 16 + j16;
#pragma unroll
        for (int q = 0; q < 4; ++q) {
          const int o = ob + q;
          const size_t idx = ((size_t)(b * C_DIM + o)) * S_DIM + s;
          y[idx] = acc[mt][nt][q] + bo[o] + resid[idx];
        }
      }
    }
  }
}

// ---------------------------------------------------------------------------
// MFMA flash attention — KVBLK=128 (R13 structure, CORRECT per R13's pass)
// with the kt loop left as a RUNTIME loop: R13's #pragma unroll let the
// compiler hoist 8 tiles' staging addresses -> VGPR 256 -> spill (31MB
// scratch writes). One body keeps live ranges bounded.
// 8 staged tiles, 2 buffers of (K[128][64] 16KB + V[64][256B] 16KB) = 64KB
// LDS, ONE __syncthreads per 128 keys (prefetch had a full tile-compute
// (~2000 cyc) in flight -> drain free). Tile = two 64-key sub-phases
// reusing sacc/pf4.
// K swizzle (row&7)<<4 (128B rows); V swizzle (row&15)<<4 (256B rows, 2-way
// bank aliasing = free per m136); both applied as inverse on the global src.
// P fully in registers (PV k-slot map key = ks*32+(idx>>2)*16+g*4+(idx&3),
// ks = sub*2+ks2; Vt global col-perm per 64-block unchanged).
// Normalization (1/l) in the epilogue (l is per (head,q) — R5 lesson).
// Grid (bh, qb): 64 x 8 = 512 blocks, 256 thr (4 waves, nt=2: 32 q/wave).
// ---------------------------------------------------------------------------
__global__ __launch_bounds__(256) void attn_mfma(
    const unsigned short* __restrict__ Qg, const unsigned short* __restrict__ Kg,
    const unsigned short* __restrict__ Vg, unsigned short* __restrict__ AOt)
{
  const int bh = blockIdx.x;   // 0..63 (fast dim -> same-XCD KV sharing)
  const int qb = blockIdx.y;   // 0..7
  const int b = bh >> 3, head = bh & 7;
  const int tid = threadIdx.x;
  const int w = tid >> 6, lane = tid & 63;
  const int g = lane >> 4, j16 = lane & 15;
  const int qw0 = qb * 128 + w * 32;  // this wave's 32 q-rows

  // [buf][ K 16KB | V 16KB ]; buf stride 32KB
  __shared__ __align__(16) unsigned short KV[2][2][8192];

  // Q B-fragments resident in registers: j=q=lane&15, k-slot (g,reg)->d
  bf16x8 qf[2][2];
#pragma unroll
  for (int nt = 0; nt < 2; ++nt)
#pragma unroll
    for (int ks = 0; ks < 2; ++ks)
      qf[nt][ks] = __builtin_bit_cast(
          bf16x8, *(const u16x8*)(Qg + ((size_t)bh * S_DIM + qw0 + nt * 16 + j16) * HD +
                                  ks * 32 + g * 8));

  // staging per 128-key tile: K 1024 chunks + V 1024 chunks over 256 thr
  // = 4+4 gload_lds/thread. dst = linear chunk*16 (wave-uniform base + lane*16).
  auto STAGE = [&](int buf, int k0) {
    unsigned short* const Kd = &KV[buf][0][0];
    unsigned short* const Vd = &KV[buf][1][0];
#pragma unroll
    for (int it = 0; it < 4; ++it) {
      const int cid = it * 256 + tid;
      // K chunk: row 0..127 (key), 128B rows, swizzle (row&7)<<4
      const int krow = cid >> 3;
      const int ksrc = ((cid & 7) << 4) ^ ((krow & 7) << 4);
      gload_lds16(Kg + ((size_t)bh * S_DIM + k0 + krow) * HD + (ksrc >> 1),
                  Kd + (size_t)(it * 256 + w * 64) * 8);
      // V chunk: row 0..63 (d), 256B rows, swizzle (row&15)<<4
      const int vrow = cid >> 4;
      const int vsrc = ((cid & 15) << 4) ^ ((vrow & 15) << 4);
      gload_lds16(Vg + ((size_t)bh * HD + vrow) * S_DIM + k0 + (vsrc >> 1),
                  Vd + (size_t)(it * 256 + w * 64) * 8);
    }
  };

  f32x4 oacc[4][2];
#pragma unroll
  for (int mt = 0; mt < 4; ++mt)
#pragma unroll
    for (int nt = 0; nt < 2; ++nt) {
      oacc[mt][nt].x = 0.f; oacc[mt][nt].y = 0.f;
      oacc[mt][nt].z = 0.f; oacc[mt][nt].w = 0.f;
    }
  float lsum[2] = {0.f, 0.f};

  STAGE(0, 0);

  for (int kt = 0; kt < 8; ++kt) {   // runtime loop — do NOT unroll (R13 spill)
    __syncthreads();  // drains prefetch (issued a full tile-compute ago) +
                      // gates overwrite of the buffer read last iteration
    if (kt < 7) STAGE((kt + 1) & 1, (kt + 1) * 128);

    const char* const Kl = (const char*)&KV[kt & 1][0][0];
    const char* const Vl = (const char*)&KV[kt & 1][1][0];

#pragma unroll
    for (int sub = 0; sub < 2; ++sub) {
      // ---- S^T = K · Q^T  (key = sub*64 + mt*16+g*4+reg, q = nt*16+j16)
      f32x4 sacc[4][2];
      __builtin_amdgcn_s_setprio(1);
#pragma unroll
      for (int mt = 0; mt < 4; ++mt) {
        const int row = sub * 64 + mt * 16 + j16;
        const int sw = (row & 7) << 4;
        const bf16x8 kf0 = __builtin_bit_cast(
            bf16x8, *(const u16x8*)(Kl + row * 128 + ((g * 16) ^ sw)));
#pragma unroll
        for (int nt = 0; nt < 2; ++nt) {
          f32x4 z; z.x = 0.f; z.y = 0.f; z.z = 0.f; z.w = 0.f;
          sacc[mt][nt] = mfma16(kf0, qf[nt][0], z);
        }
        const bf16x8 kf1 = __builtin_bit_cast(
            bf16x8, *(const u16x8*)(Kl + row * 128 + ((64 + g * 16) ^ sw)));
#pragma unroll
        for (int nt = 0; nt < 2; ++nt)
          sacc[mt][nt] = mfma16(kf1, qf[nt][1], sacc[mt][nt]);
      }
      __builtin_amdgcn_s_setprio(0);

      // ---- exp2 + pack P in registers: pf4[nt][mt] = bf16 of p[reg 0..3]
      u16x4 pf4[2][4];
#pragma unroll
      for (int mt = 0; mt < 4; ++mt)
#pragma unroll
        for (int nt = 0; nt < 2; ++nt) {
          f32x4 p;
          p.x = exp2f(sacc[mt][nt].x);
          p.y = exp2f(sacc[mt][nt].y);
          p.z = exp2f(sacc[mt][nt].z);
          p.w = exp2f(sacc[mt][nt].w);
          lsum[nt] += (p.x + p.y) + (p.z + p.w);
          pf4[nt][mt] = u16x4{f2b_hw(p.x), f2b_hw(p.y), f2b_hw(p.z), f2b_hw(p.w)};
        }

      // ---- O^T += V^T · P^T  (keys sub*64..sub*64+63; V cols sub*128 bytes on)
      __builtin_amdgcn_s_setprio(1);
#pragma unroll
      for (int ks2 = 0; ks2 < 2; ++ks2) {
        bf16x8 pfr[2];
#pragma unroll
        for (int nt = 0; nt < 2; ++nt)
          pfr[nt] = __builtin_bit_cast(
              bf16x8, __builtin_shufflevector(pf4[nt][2 * ks2], pf4[nt][2 * ks2 + 1],
                                              0, 1, 2, 3, 4, 5, 6, 7));
#pragma unroll
        for (int mt = 0; mt < 4; ++mt) {
          const int vrow = mt * 16 + j16;           // d row, 256B pitch
          const int col = (sub * 128 + ks2 * 64 + g * 16) ^ ((vrow & 15) << 4);
          const bf16x8 vf = __builtin_bit_cast(
              bf16x8, *(const u16x8*)(Vl + vrow * 256 + col));
#pragma unroll
          for (int nt = 0; nt < 2; ++nt)
            oacc[mt][nt] = mfma16(vf, pfr[nt], oacc[mt][nt]);
        }
      }
      __builtin_amdgcn_s_setprio(0);
    }
  }

  // softmax denominator: q col = lane&15; reduce across the 4 lane-groups
#pragma unroll
  for (int nt = 0; nt < 2; ++nt) {
    lsum[nt] += __shfl_xor(lsum[nt], 16);
    lsum[nt] += __shfl_xor(lsum[nt], 32);
    lsum[nt] = 1.f / lsum[nt];
  }

  // write NORMALIZED AO^T [b][s][c] bf16, c = head*64 + d; d = mt*16+g*4+r
#pragma unroll
  for (int mt = 0; mt < 4; ++mt)
#pragma unroll
    for (int nt = 0; nt < 2; ++nt) {
      const int q = qw0 + nt * 16 + j16;
      const f32x4 a = oacc[mt][nt];
      const float rl = lsum[nt];
      const u16x4 pk = {f2b_hw(a.x * rl), f2b_hw(a.y * rl), f2b_hw(a.z * rl), f2b_hw(a.w * rl)};
      *(u16x4*)(AOt + ((size_t)(b * S_DIM + q)) * C_DIM + head * HD + mt * 16 + g * 4) = pk;
    }
}

extern "C" void kernel_launch(void* const* d_in, const int* in_sizes, int n_in,
                              void* d_out, int out_size, void* d_ws, size_t ws_size,
                              hipStream_t stream) {
  const float* x    = (const float*)d_in[0];
  const float* Wqkv = (const float*)d_in[1];
  const float* Wo   = (const float*)d_in[2];
  const float* bo   = (const float*)d_in[3];
  float* y = (float*)d_out;

  unsigned short* WqkvB = (unsigned short*)d_ws;           // 786432
  unsigned short* WoB   = WqkvB + 786432;                  // 262144
  unsigned short* xT    = WoB + 262144;                    // 4194304
  unsigned short* Q     = xT + 4194304;                    // 4194304
  unsigned short* K     = Q + 4194304;
  unsigned short* Vt    = K + 4194304;
  unsigned short* AOt   = Vt + 4194304;                    // 4194304

  prep<<<dim3(2048), 256, 0, stream>>>(x, Wqkv, Wo, WqkvB, WoB, xT);
  mfma_proj<0><<<dim3(8, 12, 8), 256, 0, stream>>>(WqkvB, xT, Q, K, Vt,
                                                   nullptr, nullptr, nullptr);
  attn_mfma<<<dim3(64, 8), 256, 0, stream>>>(Q, K, Vt, AOt);
  mfma_proj<1><<<dim3(8, 4, 8), 256, 0, stream>>>(WoB, AOt, nullptr, nullptr, nullptr,
                                                  y, bo, x);
}

// Round 15
// 78.437 us; speedup vs baseline: 1.3228x; 1.1034x over previous
//
#include <hip/hip_runtime.h>
#include <hip/hip_bf16.h>

#define C_DIM 512
#define S_DIM 1024
#define NH 8
#define HD 64  // head dim

typedef __attribute__((ext_vector_type(8))) short bf16x8;            // MFMA A/B frag (8 bf16)
typedef __attribute__((ext_vector_type(8))) unsigned short u16x8;
typedef __attribute__((ext_vector_type(4))) unsigned short u16x4;
typedef __attribute__((ext_vector_type(4))) float f32x4;

__device__ __forceinline__ unsigned short f2b_hw(float f) {  // fp32 -> bf16 RNE (HW cvt)
  __hip_bfloat16 h = __float2bfloat16(f);
  return __builtin_bit_cast(unsigned short, h);
}

__device__ __forceinline__ f32x4 mfma16(bf16x8 a, bf16x8 b, f32x4 c) {
  return __builtin_amdgcn_mfma_f32_16x16x32_bf16(a, b, c, 0, 0, 0);
}

__device__ __forceinline__ void gload_lds16(const unsigned short* g, unsigned short* l) {
  __builtin_amdgcn_global_load_lds(
      (const __attribute__((address_space(1))) unsigned int*)g,
      (__attribute__((address_space(3))) unsigned int*)l, 16, 0, 0);
}

// ---------------------------------------------------------------------------
// prep: blocks [0,1024): convert Wqkv (Q-rows pre-scaled by (1/8)*log2e) and
//       Wo fp32->bf16.  blocks [1024,2048): transpose x [b][c][s] fp32 ->
//       xT [b][s][c] bf16 via 64x64 LDS tile.
// ---------------------------------------------------------------------------
__global__ __launch_bounds__(256) void prep(
    const float* __restrict__ x, const float* __restrict__ Wqkv,
    const float* __restrict__ Wo,
    unsigned short* __restrict__ WqkvB, unsigned short* __restrict__ WoB,
    unsigned short* __restrict__ xT)
{
  __shared__ float T[64][65];
  const int bid = blockIdx.x;
  if (bid < 1024) {
    const int i = bid * 256 + threadIdx.x;  // handles 4 elements
    const float* src;
    unsigned short* dst;
    int off;
    float mul = 1.0f;
    if (i < 196608) {
      src = Wqkv; dst = WqkvB; off = i * 4;
      const int o = off >> 9;               // row of Wqkv
      if ((o % 192) < 64) mul = 0.18033688011112042f;  // Q rows: (1/8)*log2(e)
    } else {
      src = Wo; dst = WoB; off = (i - 196608) * 4;
    }
    const float4 v = *(const float4*)(src + off);
    const u16x4 pk = {f2b_hw(v.x * mul), f2b_hw(v.y * mul),
                      f2b_hw(v.z * mul), f2b_hw(v.w * mul)};
    *(u16x4*)(dst + off) = pk;
  } else {
    const int idx = bid - 1024;
    const int st = idx & 15, ct = (idx >> 4) & 7, b = idx >> 7;
    const int c0 = ct * 64, s0 = st * 64;
    const int tr = threadIdx.x >> 4, tc4 = (threadIdx.x & 15) * 4;
#pragma unroll
    for (int rep = 0; rep < 4; ++rep) {
      const int c = rep * 16 + tr;
      *(float4*)&T[c][tc4] =
          *(const float4*)(x + ((size_t)(b * C_DIM + c0 + c)) * S_DIM + s0 + tc4);
    }
    __syncthreads();
#pragma unroll
    for (int rep = 0; rep < 4; ++rep) {
      const int s = rep * 16 + tr;
      const u16x4 pk = {f2b_hw(T[tc4 + 0][s]), f2b_hw(T[tc4 + 1][s]),
                        f2b_hw(T[tc4 + 2][s]), f2b_hw(T[tc4 + 3][s])};
      *(u16x4*)(xT + ((size_t)(b * S_DIM + s0 + s)) * C_DIM + c0 + tc4) = pk;
    }
  }
}

// ---------------------------------------------------------------------------
// proj_qkv (m97 structure, unchanged since R7): C[o][s] = sum_c W[o][c]*xT[b][s][c]
// 128x128 tile, BK=64, 4 waves (2x2 of 64x64). Scatter bf16 Q/K -> [bh][s][d];
// Vt -> [bh][d][s] with within-64 col perm p = (s&35)|((s&12)<<1)|((s&16)>>2)
// so attn's PV A-fragment is one contiguous ds_read_b128.
// ---------------------------------------------------------------------------
__global__ __launch_bounds__(256) void proj_qkv(
    const unsigned short* __restrict__ A, const unsigned short* __restrict__ Bm,
    unsigned short* __restrict__ Q, unsigned short* __restrict__ K,
    unsigned short* __restrict__ Vt)
{
  const int b = blockIdx.z, ot = blockIdx.y, st = blockIdx.x;
  const int o0 = ot * 128, s0 = st * 128;
  const int tid = threadIdx.x;
  const int w = tid >> 6, lane = tid & 63;
  const int g = lane >> 4, j16 = lane & 15;
  const int wr = w >> 1, wc = w & 1;

  __shared__ __align__(16) unsigned short lds[2048 * 8];  // 32KB: A[128][64] | B[128][64]
  char* const Al = (char*)lds;
  char* const Bl = (char*)lds + 16384;

  f32x4 acc[4][4];
#pragma unroll
  for (int mt = 0; mt < 4; ++mt)
#pragma unroll
    for (int nt = 0; nt < 4; ++nt) {
      acc[mt][nt].x = 0.f; acc[mt][nt].y = 0.f;
      acc[mt][nt].z = 0.f; acc[mt][nt].w = 0.f;
    }

  for (int k0 = 0; k0 < C_DIM; k0 += 64) {
    __syncthreads();
#pragma unroll
    for (int it = 0; it < 8; ++it) {
      const int chunk = it * 256 + tid;
      const int cid = chunk & 1023;
      const int row = cid >> 3;
      const int colb = (cid & 7) << 4;
      const int srcb = colb ^ ((row & 7) << 4);
      const unsigned short* gp;
      if (it < 4) gp = A + (size_t)(o0 + row) * C_DIM + k0 + (srcb >> 1);
      else        gp = Bm + ((size_t)(b * S_DIM) + s0 + row) * C_DIM + k0 + (srcb >> 1);
      gload_lds16(gp, lds + (size_t)(it * 256 + w * 64) * 8);
    }
    __syncthreads();

#pragma unroll
    for (int ks = 0; ks < 2; ++ks) {
      bf16x8 af[4], bfr[4];
#pragma unroll
      for (int mt = 0; mt < 4; ++mt) {
        const int r = wr * 64 + mt * 16 + j16;
        af[mt] = __builtin_bit_cast(
            bf16x8, *(const u16x8*)(Al + r * 128 + ((ks * 64 + g * 16) ^ ((r & 7) << 4))));
      }
#pragma unroll
      for (int nt = 0; nt < 4; ++nt) {
        const int r = wc * 64 + nt * 16 + j16;
        bfr[nt] = __builtin_bit_cast(
            bf16x8, *(const u16x8*)(Bl + r * 128 + ((ks * 64 + g * 16) ^ ((r & 7) << 4))));
      }
#pragma unroll
      for (int mt = 0; mt < 4; ++mt)
#pragma unroll
        for (int nt = 0; nt < 4; ++nt)
          acc[mt][nt] = mfma16(af[mt], bfr[nt], acc[mt][nt]);
    }
  }

#pragma unroll
  for (int mt = 0; mt < 4; ++mt) {
    const int ob = o0 + wr * 64 + mt * 16 + g * 4;
    const int head = ob / 192, type = (ob % 192) >> 6, d = ob & 63;
    const int bh = b * NH + head;
    if (type < 2) {
      unsigned short* const dst = (type == 0) ? Q : K;
#pragma unroll
      for (int nt = 0; nt < 4; ++nt) {
        const int s = s0 + wc * 64 + nt * 16 + j16;
        const f32x4 a = acc[mt][nt];
        const u16x4 pk = {f2b_hw(a.x), f2b_hw(a.y), f2b_hw(a.z), f2b_hw(a.w)};
        *(u16x4*)(dst + ((size_t)bh * S_DIM + s) * HD + d) = pk;
      }
    } else {
#pragma unroll
      for (int nt = 0; nt < 4; ++nt) {
        const int spos = nt * 16 + j16;
        const int p = (spos & 35) | ((spos & 12) << 1) | ((spos & 16) >> 2);
        const size_t col = (size_t)(s0 + wc * 64 + p);
        const f32x4 a = acc[mt][nt];
#pragma unroll
        for (int q = 0; q < 4; ++q)
          Vt[((size_t)bh * HD + d + q) * S_DIM + col] = f2b_hw(a[q]);
      }
    }
  }
}

// ---------------------------------------------------------------------------
// proj_out — 64x128 tile (was 128x128): grid 8x8x8 = 512 blocks = 2/CU
// (old 256 blocks = 1/CU left every staging drain exposed — same failure
// mode as attn R4). 4 waves each own 64x32 (acc[4][2], ~70 VGPR); LDS 24KB
// (A[64][64] 8KB + B[128][64] 16KB). Same m97 2-barrier loop + T2 swizzle.
// y = C + bo + resid (fp32, [b][o][s]).
// ---------------------------------------------------------------------------
__global__ __launch_bounds__(256) void proj_out(
    const unsigned short* __restrict__ A, const unsigned short* __restrict__ Bm,
    float* __restrict__ y, const float* __restrict__ bo,
    const float* __restrict__ resid)
{
  const int b = blockIdx.z, ot = blockIdx.y, st = blockIdx.x;
  const int o0 = ot * 64, s0 = st * 128;
  const int tid = threadIdx.x;
  const int w = tid >> 6, lane = tid & 63;
  const int g = lane >> 4, j16 = lane & 15;

  __shared__ __align__(16) unsigned short lds[1536 * 8];  // 24KB: A[64][64] | B[128][64]
  char* const Al = (char*)lds;
  char* const Bl = (char*)lds + 8192;

  f32x4 acc[4][2];
#pragma unroll
  for (int mt = 0; mt < 4; ++mt)
#pragma unroll
    for (int nt = 0; nt < 2; ++nt) {
      acc[mt][nt].x = 0.f; acc[mt][nt].y = 0.f;
      acc[mt][nt].z = 0.f; acc[mt][nt].w = 0.f;
    }

  for (int k0 = 0; k0 < C_DIM; k0 += 64) {
    __syncthreads();
    // A: 512 chunks (it 0..1), B: 1024 chunks (it 2..5); 6 loads/thread
#pragma unroll
    for (int it = 0; it < 6; ++it) {
      const int cid = (it < 2) ? (it * 256 + tid) : ((it - 2) * 256 + tid);
      const int row = cid >> 3;
      const int srcb = ((cid & 7) << 4) ^ ((row & 7) << 4);
      if (it < 2) {
        gload_lds16(A + (size_t)(o0 + row) * C_DIM + k0 + (srcb >> 1),
                    lds + (size_t)(it * 256 + w * 64) * 8);
      } else {
        gload_lds16(Bm + ((size_t)(b * S_DIM) + s0 + row) * C_DIM + k0 + (srcb >> 1),
                    lds + (size_t)(512 + (it - 2) * 256 + w * 64) * 8);
      }
    }
    __syncthreads();

#pragma unroll
    for (int ks = 0; ks < 2; ++ks) {
      bf16x8 af[4], bfr[2];
#pragma unroll
      for (int mt = 0; mt < 4; ++mt) {
        const int r = mt * 16 + j16;                 // o row 0..63
        af[mt] = __builtin_bit_cast(
            bf16x8, *(const u16x8*)(Al + r * 128 + ((ks * 64 + g * 16) ^ ((r & 7) << 4))));
      }
#pragma unroll
      for (int nt = 0; nt < 2; ++nt) {
        const int r = w * 32 + nt * 16 + j16;        // s row 0..127
        bfr[nt] = __builtin_bit_cast(
            bf16x8, *(const u16x8*)(Bl + r * 128 + ((ks * 64 + g * 16) ^ ((r & 7) << 4))));
      }
#pragma unroll
      for (int mt = 0; mt < 4; ++mt)
#pragma unroll
        for (int nt = 0; nt < 2; ++nt)
          acc[mt][nt] = mfma16(af[mt], bfr[nt], acc[mt][nt]);
    }
  }

  // epilogue: o = o0 + mt*16 + g*4 + q ; s = s0 + w*32 + nt*16 + j16
#pragma unroll
  for (int mt = 0; mt < 4; ++mt) {
    const int ob = o0 + mt * 16 + g * 4;
#pragma unroll
    for (int nt = 0; nt < 2; ++nt) {
      const int s = s0 + w * 32 + nt * 16 + j16;
#pragma unroll
      for (int q = 0; q < 4; ++q) {
        const int o = ob + q;
        const size_t idx = ((size_t)(b * C_DIM + o)) * S_DIM + s;
        y[idx] = acc[mt][nt][q] + bo[o] + resid[idx];
      }
    }
  }
}

// ---------------------------------------------------------------------------
// MFMA flash attention — R11 exact (best measured: 81.57us total). QBLK=128,
// 8 waves (512 thr), each wave 16 q-rows; 3-buffer counted-vmcnt ring:
//   tile kt: vmcnt(2) [kt's 2 loads done, kt+1's in flight] -> s_barrier ->
//            STAGE(kt+2) -> QK^T -> exp2/pack (P in registers) -> PV
// P fully in registers (PV k-slot map key = ks*32+(idx>>2)*16+g*4+(idx&3);
// Vt global layout pre-permuted so V A-frag is one ds_read_b128).
// Normalization (1/l) in the epilogue (l is per (head,q) — R5 lesson).
// Grid (bh, qb): blocks sharing a head's K/V are id-strided by 64 -> same XCD.
// FROZEN: R9 (T15 dbl-pipe: spill), R10 (QBLK=64: 2x staging), R12 (QBLK=256:
// neutral), R13/R14 (KVBLK=128: spill / slower) all failed to beat this.
// ---------------------------------------------------------------------------
__global__ __launch_bounds__(512) void attn_mfma(
    const unsigned short* __restrict__ Qg, const unsigned short* __restrict__ Kg,
    const unsigned short* __restrict__ Vg, unsigned short* __restrict__ AOt)
{
  const int bh = blockIdx.x;   // 0..63 (fast dim -> same-XCD KV sharing)
  const int qb = blockIdx.y;   // 0..7
  const int b = bh >> 3, head = bh & 7;
  const int tid = threadIdx.x;
  const int w = tid >> 6, lane = tid & 63;   // 8 waves
  const int g = lane >> 4, j16 = lane & 15;
  const int qw0 = qb * 128 + w * 16;  // this wave's 16 q-rows

  __shared__ __align__(16) unsigned short KV[3][2][4096];  // 48KB ring: [buf][K/V][64x64]

  // Q B-fragment resident in registers: j=q=lane&15, k-slot (g,reg)->d
  bf16x8 qf[2];
#pragma unroll
  for (int ks = 0; ks < 2; ++ks)
    qf[ks] = __builtin_bit_cast(
        bf16x8, *(const u16x8*)(Qg + ((size_t)bh * S_DIM + qw0 + j16) * HD +
                                ks * 32 + g * 8));

  // staging: 512 x 16B chunks per tensor over 512 threads = 1 chunk each
  // per tensor (2 loads/thread). dst is wave-uniform; lane offset automatic.
  auto STAGE = [&](int buf, int k0) {
    const int cid = tid;                      // w*64 + lane
    const int row = cid >> 3;
    const int srcb = ((cid & 7) << 4) ^ ((row & 7) << 4);  // inverse swizzle on src
    unsigned short* const dst = &KV[buf][0][0] + (size_t)(w * 64) * 8;
    gload_lds16(Kg + ((size_t)bh * S_DIM + k0 + row) * HD + (srcb >> 1), dst);
    gload_lds16(Vg + ((size_t)bh * HD + row) * S_DIM + k0 + (srcb >> 1), dst + 4096);
  };

  f32x4 oacc[4];
#pragma unroll
  for (int mt = 0; mt < 4; ++mt) {
    oacc[mt].x = 0.f; oacc[mt].y = 0.f; oacc[mt].z = 0.f; oacc[mt].w = 0.f;
  }
  float lsum = 0.f;

  STAGE(0, 0);
  STAGE(1, 64);

  for (int kt = 0; kt < 16; ++kt) {
    // wait for THIS tile's 2 loads (oldest); keep next tile's 2 in flight
    if (kt < 15) asm volatile("s_waitcnt vmcnt(2)" ::: "memory");
    else         asm volatile("s_waitcnt vmcnt(0)" ::: "memory");
    __builtin_amdgcn_s_barrier();  // all waves' kt loads visible; slot (kt+2)%3
                                   // was last read in tile kt-1 -> reusable
    if (kt < 14) STAGE((kt + 2) % 3, (kt + 2) * 64);

    const char* const Kl = (const char*)KV + (kt % 3) * 16384;
    const char* const Vl = Kl + 8192;

    // ---- S^T = K · Q^T  (key = mt*16+g*4+reg, q = j16)
    f32x4 sacc[4];
    __builtin_amdgcn_s_setprio(1);
#pragma unroll
    for (int mt = 0; mt < 4; ++mt) {
      const int row = mt * 16 + j16;
      const int sw = (row & 7) << 4;
      const bf16x8 kf0 = __builtin_bit_cast(
          bf16x8, *(const u16x8*)(Kl + row * 128 + ((g * 16) ^ sw)));
      f32x4 z; z.x = 0.f; z.y = 0.f; z.z = 0.f; z.w = 0.f;
      sacc[mt] = mfma16(kf0, qf[0], z);
      const bf16x8 kf1 = __builtin_bit_cast(
          bf16x8, *(const u16x8*)(Kl + row * 128 + ((64 + g * 16) ^ sw)));
      sacc[mt] = mfma16(kf1, qf[1], sacc[mt]);
    }
    __builtin_amdgcn_s_setprio(0);

    // ---- exp2 + pack P in registers: pf4[mt] = bf16 of p[reg 0..3]
    u16x4 pf4[4];
#pragma unroll
    for (int mt = 0; mt < 4; ++mt) {
      f32x4 p;
      p.x = exp2f(sacc[mt].x);
      p.y = exp2f(sacc[mt].y);
      p.z = exp2f(sacc[mt].z);
      p.w = exp2f(sacc[mt].w);
      lsum += (p.x + p.y) + (p.z + p.w);
      pf4[mt] = u16x4{f2b_hw(p.x), f2b_hw(p.y), f2b_hw(p.z), f2b_hw(p.w)};
    }

    // ---- O^T += V^T · P^T   (k-slot map: key = ks*32 + (idx>>2)*16 + g*4 + (idx&3))
    __builtin_amdgcn_s_setprio(1);
#pragma unroll
    for (int ks = 0; ks < 2; ++ks) {
      const bf16x8 pfr = __builtin_bit_cast(
          bf16x8, __builtin_shufflevector(pf4[2 * ks], pf4[2 * ks + 1],
                                          0, 1, 2, 3, 4, 5, 6, 7));
#pragma unroll
      for (int mt = 0; mt < 4; ++mt) {
        const int row = mt * 16 + j16;
        const int sw = (row & 7) << 4;
        const bf16x8 vf = __builtin_bit_cast(
            bf16x8, *(const u16x8*)(Vl + row * 128 + ((ks * 64 + g * 16) ^ sw)));
        oacc[mt] = mfma16(vf, pfr, oacc[mt]);
      }
    }
    __builtin_amdgcn_s_setprio(0);
  }

  // softmax denominator: q col = lane&15; reduce across the 4 lane-groups
  lsum += __shfl_xor(lsum, 16);
  lsum += __shfl_xor(lsum, 32);
  const float rl = 1.f / lsum;

  // write NORMALIZED AO^T [b][s][c] bf16, c = head*64 + d; d = mt*16+g*4+r
  const int q = qw0 + j16;
#pragma unroll
  for (int mt = 0; mt < 4; ++mt) {
    const f32x4 a = oacc[mt];
    const u16x4 pk = {f2b_hw(a.x * rl), f2b_hw(a.y * rl), f2b_hw(a.z * rl), f2b_hw(a.w * rl)};
    *(u16x4*)(AOt + ((size_t)(b * S_DIM + q)) * C_DIM + head * HD + mt * 16 + g * 4) = pk;
  }
}

extern "C" void kernel_launch(void* const* d_in, const int* in_sizes, int n_in,
                              void* d_out, int out_size, void* d_ws, size_t ws_size,
                              hipStream_t stream) {
  const float* x    = (const float*)d_in[0];
  const float* Wqkv = (const float*)d_in[1];
  const float* Wo   = (const float*)d_in[2];
  const float* bo   = (const float*)d_in[3];
  float* y = (float*)d_out;

  unsigned short* WqkvB = (unsigned short*)d_ws;           // 786432
  unsigned short* WoB   = WqkvB + 786432;                  // 262144
  unsigned short* xT    = WoB + 262144;                    // 4194304
  unsigned short* Q     = xT + 4194304;                    // 4194304
  unsigned short* K     = Q + 4194304;
  unsigned short* Vt    = K + 4194304;
  unsigned short* AOt   = Vt + 4194304;                    // 4194304

  prep<<<dim3(2048), 256, 0, stream>>>(x, Wqkv, Wo, WqkvB, WoB, xT);
  proj_qkv<<<dim3(8, 12, 8), 256, 0, stream>>>(WqkvB, xT, Q, K, Vt);
  attn_mfma<<<dim3(64, 8), 512, 0, stream>>>(Q, K, Vt, AOt);
  proj_out<<<dim3(8, 8, 8), 256, 0, stream>>>(WoB, AOt, y, bo, x);
}